// Round 2
// baseline (210.869 us; speedup 1.0000x reference)
//
#include <hip/hip_runtime.h>
#include <hip/hip_fp16.h>

typedef __attribute__((ext_vector_type(8))) _Float16 f16x8;
typedef __attribute__((ext_vector_type(4))) float f32x4;

#define MFMA16(a, b, c) __builtin_amdgcn_mfma_f32_16x16x32_f16((a), (b), (c), 0, 0, 0)

__device__ __forceinline__ unsigned short f2h(float f) {
  __half h = __float2half(f);  // v_cvt_f16_f32, RNE
  return __half_as_ushort(h);
}

// ---------------- f32 -> fp16 convert (vectorized) ----------------
__global__ void cvt_f16_kernel(const float* __restrict__ X, unsigned short* __restrict__ Y) {
  size_t i = ((size_t)blockIdx.x * blockDim.x + threadIdx.x) * 4;
  float4 v = *reinterpret_cast<const float4*>(X + i);
  ushort4 o;
  o.x = f2h(v.x); o.y = f2h(v.y); o.z = f2h(v.z); o.w = f2h(v.w);
  *reinterpret_cast<ushort4*>(Y + i) = o;
}

// ---------------- weight transpose f32(RxC) -> fp16(CxR) ----------------
__global__ void transpose_w_kernel(const float* __restrict__ W, unsigned short* __restrict__ WT,
                                   int R, int C) {
  __shared__ float tile[32][33];
  int c0 = blockIdx.x * 32, r0 = blockIdx.y * 32;
  int tx = threadIdx.x, ty = threadIdx.y;  // 32 x 8
#pragma unroll
  for (int i = 0; i < 32; i += 8)
    tile[ty + i][tx] = W[(size_t)(r0 + ty + i) * C + c0 + tx];
  __syncthreads();
#pragma unroll
  for (int i = 0; i < 32; i += 8)
    WT[(size_t)(c0 + ty + i) * R + r0 + tx] = f2h(tile[tx][ty + i]);
}

// ---------------- positional embedding: pos[2048][192] fp16 (row 2047 = 0) ----------------
__global__ void posembed_kernel(unsigned short* __restrict__ pos) {
  int d = blockIdx.x * blockDim.x + threadIdx.x;
  if (d >= 2048) return;
  unsigned short* row = pos + (size_t)d * 192;
  if (d == 2047) {
    for (int j = 0; j < 192; ++j) row[j] = 0;
    return;
  }
  float dist = (float)d - 1023.0f;
  float absd = fabsf(dist);
  float sgnp = (dist > 0.0f) ? 1.0f : ((dist < 0.0f) ? -1.0f : 0.0f);
  float gam[32];
  float maxp = 0.0f;
#pragma unroll
  for (int j = 0; j < 32; ++j) {
    float hl = exp2f(3.0f + (float)j * (7.0f / 31.0f));   // 2^linspace(3,10,32)
    float fe = exp2f(-absd / hl);                          // exp(-ln2/hl * absd)
    float cw = exp2f((float)(j + 1)) - 1.0f;
    float fc = (cw > absd) ? 1.0f : 0.0f;
    float jp = (float)(j + 1);
    float conc = 4.0f * jp * jp;        // (mean/std)^2, mean=32(j+1), std=16
    float rate = 0.125f * jp;           // mean/std^2
    float lu = (conc - 1.0f) * logf(absd) - rate * absd;   // absd=0 -> -inf (matches xlogy)
    float ln_ = lgammaf(conc) - conc * logf(rate);
    float p = expf(lu - ln_) + 1e-8f;
    gam[j] = p;
    maxp = fmaxf(maxp, p);
    row[j] = f2h(fe);
    row[32 + j] = f2h(fc);
  }
  float inv = 1.0f / maxp;
#pragma unroll
  for (int j = 0; j < 32; ++j) row[64 + j] = f2h(gam[j] * inv);
  for (int j = 0; j < 96; ++j) {
    unsigned short v = row[j];
    unsigned short o;
    if (sgnp == 0.0f) o = 0;
    else if (sgnp > 0.0f) o = v;
    else o = (unsigned short)(v ^ 0x8000u);
    row[96 + j] = o;
  }
}

// ---------------- generic fp16 GEMM: C[m][n] = sum_k A[m][k]*BT[n][k] (+bias[n]) ----------------
// 128x128 tile, 4 waves (2x2), K-step 32. z selects among 3 (BT,C) pairs (QKV batching).
__global__ __launch_bounds__(256) void gemm_bt_kernel(
    const unsigned short* __restrict__ A,
    const unsigned short* __restrict__ BT0, const unsigned short* __restrict__ BT1,
    const unsigned short* __restrict__ BT2,
    float* __restrict__ C0, float* __restrict__ C1, float* __restrict__ C2,
    const float* __restrict__ bias, int M, int N, int K) {
  __shared__ unsigned short As[128][40];
  __shared__ unsigned short Bs[128][40];
  const unsigned short* BT = (blockIdx.z == 0) ? BT0 : ((blockIdx.z == 1) ? BT1 : BT2);
  float* C = (blockIdx.z == 0) ? C0 : ((blockIdx.z == 1) ? C1 : C2);

  int tid = threadIdx.x;
  int wave = tid >> 6, lane = tid & 63;
  int g = lane >> 4, r16 = lane & 15;
  int m0 = blockIdx.x * 128, n0 = blockIdx.y * 128;
  int wr = wave >> 1, wc = wave & 1;
  f32x4 acc[4][4] = {};
  int sr = tid >> 1, scc = (tid & 1) * 16;

  for (int k0 = 0; k0 < K; k0 += 32) {
    __syncthreads();
    {
      const unsigned short* srcA = A + (size_t)(m0 + sr) * K + k0 + scc;
      uint4 a0 = *reinterpret_cast<const uint4*>(srcA);
      uint4 a1 = *reinterpret_cast<const uint4*>(srcA + 8);
      const unsigned short* srcB = BT + (size_t)(n0 + sr) * K + k0 + scc;
      uint4 b0 = *reinterpret_cast<const uint4*>(srcB);
      uint4 b1 = *reinterpret_cast<const uint4*>(srcB + 8);
      *reinterpret_cast<uint4*>(&As[sr][scc]) = a0;
      *reinterpret_cast<uint4*>(&As[sr][scc + 8]) = a1;
      *reinterpret_cast<uint4*>(&Bs[sr][scc]) = b0;
      *reinterpret_cast<uint4*>(&Bs[sr][scc + 8]) = b1;
    }
    __syncthreads();
    f16x8 af[4], bfr[4];
#pragma unroll
    for (int mt = 0; mt < 4; ++mt)
      af[mt] = *reinterpret_cast<const f16x8*>(&As[wr * 64 + mt * 16 + r16][g * 8]);
#pragma unroll
    for (int nt = 0; nt < 4; ++nt)
      bfr[nt] = *reinterpret_cast<const f16x8*>(&Bs[wc * 64 + nt * 16 + r16][g * 8]);
#pragma unroll
    for (int mt = 0; mt < 4; ++mt)
#pragma unroll
      for (int nt = 0; nt < 4; ++nt)
        acc[mt][nt] = MFMA16(af[mt], bfr[nt], acc[mt][nt]);
  }

#pragma unroll
  for (int nt = 0; nt < 4; ++nt) {
    int col = n0 + wc * 64 + nt * 16 + r16;
    float bv = bias ? bias[col] : 0.0f;
#pragma unroll
    for (int mt = 0; mt < 4; ++mt) {
      int rowb = m0 + wr * 64 + mt * 16 + g * 4;
#pragma unroll
      for (int rg = 0; rg < 4; ++rg)
        C[(size_t)(rowb + rg) * N + col] = acc[mt][nt][rg] + bv;
    }
  }
}

// ---------------- V transpose prep: Vproj f32 (2048 x 1024) -> Vt fp16 [bh][128][1024] ----------------
__global__ void vt_prep_kernel(const float* __restrict__ Vproj, unsigned short* __restrict__ Vt) {
  __shared__ float tile[32][33];
  int bh = blockIdx.z;
  int b = bh >> 3, h = bh & 7;
  int l0 = blockIdx.x * 32, n0 = blockIdx.y * 32;
  int tx = threadIdx.x, ty = threadIdx.y;
#pragma unroll
  for (int i = 0; i < 32; i += 8)
    tile[ty + i][tx] = Vproj[(size_t)(b * 1024 + l0 + ty + i) * 1024 + h * 128 + n0 + tx];
  __syncthreads();
#pragma unroll
  for (int i = 0; i < 32; i += 8)
    Vt[(size_t)bh * 131072 + (size_t)(n0 + ty + i) * 1024 + l0 + tx] = f2h(tile[tx][ty + i]);
}

// ---------------- fused attention ----------------
// grid (L/64, B*H); 256 thr = 4 waves; wave owns 16 q rows; BK=32; online softmax.
// S[q,k] = Qa[q].K[k] + Qb[q].relk[1023+k-q]
__global__ __launch_bounds__(256) void attn_kernel(
    const float* __restrict__ Qproj, const unsigned short* __restrict__ Kh,
    const unsigned short* __restrict__ Vt, const unsigned short* __restrict__ relkh,
    const float* __restrict__ eb, const float* __restrict__ pb,
    unsigned short* __restrict__ Oout) {
  __shared__ unsigned short Ks[32][136];
  __shared__ unsigned short Vs[128][40];
  __shared__ unsigned short Rs[96][136];
  __shared__ float Ws[4][16][51];
  __shared__ unsigned short Ps[4][16][40];

  int tid = threadIdx.x;
  int wave = tid >> 6, lane = tid & 63;
  int g = lane >> 4, r16 = lane & 15;
  int bh = blockIdx.y;
  int b = bh >> 3, h = bh & 7;
  int q0 = blockIdx.x * 64;
  int q0w = q0 + wave * 16;
  const float scale = 0.0883883476483184f;  // 128^-0.5

  // ---- load Q fragments (A-layout: row = lane&15, k = (lane>>4)*8+i), two bias variants
  f16x8 qa[4], qbv[4];
  {
    int qrow = b * 1024 + q0w + r16;
    const float* qp = Qproj + (size_t)qrow * 1024 + h * 128;
    const float* ebp = eb + h * 128;
    const float* pbp = pb + h * 128;
#pragma unroll
    for (int kf = 0; kf < 4; ++kf) {
      int dbase = kf * 32 + g * 8;
      float4 p0 = *reinterpret_cast<const float4*>(qp + dbase);
      float4 p1 = *reinterpret_cast<const float4*>(qp + dbase + 4);
      float4 e0 = *reinterpret_cast<const float4*>(ebp + dbase);
      float4 e1 = *reinterpret_cast<const float4*>(ebp + dbase + 4);
      float4 c0 = *reinterpret_cast<const float4*>(pbp + dbase);
      float4 c1 = *reinterpret_cast<const float4*>(pbp + dbase + 4);
      float pv[8] = {p0.x, p0.y, p0.z, p0.w, p1.x, p1.y, p1.z, p1.w};
      float ev[8] = {e0.x, e0.y, e0.z, e0.w, e1.x, e1.y, e1.z, e1.w};
      float bv[8] = {c0.x, c0.y, c0.z, c0.w, c1.x, c1.y, c1.z, c1.w};
      unsigned short ta[8], tb[8];
#pragma unroll
      for (int i = 0; i < 8; ++i) {
        float s = pv[i] * scale;
        ta[i] = f2h(s + ev[i]);
        tb[i] = f2h(s + bv[i]);
      }
      qa[kf] = *reinterpret_cast<f16x8*>(ta);
      qbv[kf] = *reinterpret_cast<f16x8*>(tb);
    }
  }

  float m_run[4], l_run[4];
#pragma unroll
  for (int rg = 0; rg < 4; ++rg) { m_run[rg] = -1e30f; l_run[rg] = 0.0f; }
  f32x4 o_acc[8] = {};

  for (int kt = 0; kt < 32; ++kt) {
    int k0 = kt * 32;
    __syncthreads();
    // stage K tile (32 rows x 128 dims, fp16)
    {
      int rr = tid >> 3, cc = (tid & 7) * 16;
      const unsigned short* src = Kh + (size_t)(b * 1024 + k0 + rr) * 1024 + h * 128 + cc;
      uint4 v0 = *reinterpret_cast<const uint4*>(src);
      uint4 v1 = *reinterpret_cast<const uint4*>(src + 8);
      *reinterpret_cast<uint4*>(&Ks[rr][cc]) = v0;
      *reinterpret_cast<uint4*>(&Ks[rr][cc + 8]) = v1;
    }
    // stage V^T tile (128 v-dims x 32 k, fp16)
    {
      int rr = tid >> 1, cc = (tid & 1) * 16;
      const unsigned short* src = Vt + (size_t)bh * 131072 + (size_t)rr * 1024 + k0 + cc;
      uint4 v0 = *reinterpret_cast<const uint4*>(src);
      uint4 v1 = *reinterpret_cast<const uint4*>(src + 8);
      *reinterpret_cast<uint4*>(&Vs[rr][cc]) = v0;
      *reinterpret_cast<uint4*>(&Vs[rr][cc + 8]) = v1;
    }
    // stage rel_k span: rows base..base+95, base = 1023+k0-q0-63
    {
      int base = 960 + k0 - q0;
      int cc = (tid & 7) * 16;
#pragma unroll
      for (int j = 0; j < 3; ++j) {
        int i = (tid >> 3) + j * 32;
        const unsigned short* src = relkh + (size_t)(base + i) * 1024 + h * 128 + cc;
        uint4 v0 = *reinterpret_cast<const uint4*>(src);
        uint4 v1 = *reinterpret_cast<const uint4*>(src + 8);
        *reinterpret_cast<uint4*>(&Rs[i][cc]) = v0;
        *reinterpret_cast<uint4*>(&Rs[i][cc + 8]) = v1;
      }
    }
    __syncthreads();

    // S1 = Qa . K^T  (16 x 32)
    f32x4 s0 = {0.f, 0.f, 0.f, 0.f}, s1 = {0.f, 0.f, 0.f, 0.f};
#pragma unroll
    for (int kf = 0; kf < 4; ++kf) {
      f16x8 kb0 = *reinterpret_cast<const f16x8*>(&Ks[r16][kf * 32 + g * 8]);
      f16x8 kb1 = *reinterpret_cast<const f16x8*>(&Ks[16 + r16][kf * 32 + g * 8]);
      s0 = MFMA16(qa[kf], kb0, s0);
      s1 = MFMA16(qa[kf], kb1, s1);
    }
    // W = Qb . RKspan^T (16 x 48); wave's span offset inside Rs = 48-16*wave
    f32x4 w0 = {0.f, 0.f, 0.f, 0.f}, w1 = {0.f, 0.f, 0.f, 0.f}, w2 = {0.f, 0.f, 0.f, 0.f};
    int wbase = 48 - wave * 16;
#pragma unroll
    for (int kf = 0; kf < 4; ++kf) {
      f16x8 rb0 = *reinterpret_cast<const f16x8*>(&Rs[wbase + r16][kf * 32 + g * 8]);
      f16x8 rb1 = *reinterpret_cast<const f16x8*>(&Rs[wbase + 16 + r16][kf * 32 + g * 8]);
      f16x8 rb2 = *reinterpret_cast<const f16x8*>(&Rs[wbase + 32 + r16][kf * 32 + g * 8]);
      w0 = MFMA16(qbv[kf], rb0, w0);
      w1 = MFMA16(qbv[kf], rb1, w1);
      w2 = MFMA16(qbv[kf], rb2, w2);
    }
    // W -> per-wave LDS, then diagonal gather: S2[q'][k'] = W[q'][k'-q'+15]
#pragma unroll
    for (int rg = 0; rg < 4; ++rg) {
      Ws[wave][g * 4 + rg][r16] = w0[rg];
      Ws[wave][g * 4 + rg][16 + r16] = w1[rg];
      Ws[wave][g * 4 + rg][32 + r16] = w2[rg];
    }
    float sv[2][4];
#pragma unroll
    for (int rg = 0; rg < 4; ++rg) {
      int qp = g * 4 + rg;
      sv[0][rg] = s0[rg] + Ws[wave][qp][r16 - qp + 15];
      sv[1][rg] = s1[rg] + Ws[wave][qp][r16 + 16 - qp + 15];
    }
    // online softmax (rows live in 16-lane groups; cols = r16 + 16*nt)
#pragma unroll
    for (int rg = 0; rg < 4; ++rg) {
      float mx = fmaxf(sv[0][rg], sv[1][rg]);
#pragma unroll
      for (int off = 8; off >= 1; off >>= 1) mx = fmaxf(mx, __shfl_xor(mx, off));
      float mnew = fmaxf(m_run[rg], mx);
      float scl = __expf(m_run[rg] - mnew);
      float e0 = __expf(sv[0][rg] - mnew);
      float e1 = __expf(sv[1][rg] - mnew);
      float rs = e0 + e1;
#pragma unroll
      for (int off = 8; off >= 1; off >>= 1) rs += __shfl_xor(rs, off);
      l_run[rg] = l_run[rg] * scl + rs;
      m_run[rg] = mnew;
#pragma unroll
      for (int nf = 0; nf < 8; ++nf) o_acc[nf][rg] *= scl;
      Ps[wave][g * 4 + rg][r16] = f2h(e0);
      Ps[wave][g * 4 + rg][16 + r16] = f2h(e1);
    }
    // PV: O += P (16x32) . V (32x128)
    f16x8 pf = *reinterpret_cast<const f16x8*>(&Ps[wave][r16][g * 8]);
#pragma unroll
    for (int nf = 0; nf < 8; ++nf) {
      f16x8 vb = *reinterpret_cast<const f16x8*>(&Vs[nf * 16 + r16][g * 8]);
      o_acc[nf] = MFMA16(pf, vb, o_acc[nf]);
    }
  }

  // epilogue: O /= l, write fp16 at [b*1024+q][h*128+n]
#pragma unroll
  for (int rg = 0; rg < 4; ++rg) {
    float inv = 1.0f / l_run[rg];
    int row = b * 1024 + q0w + g * 4 + rg;
    unsigned short* op = Oout + (size_t)row * 1024 + h * 128;
#pragma unroll
    for (int nf = 0; nf < 8; ++nf) op[nf * 16 + r16] = f2h(o_acc[nf][rg] * inv);
  }
}

// ---------------- launch ----------------
extern "C" void kernel_launch(void* const* d_in, const int* in_sizes, int n_in,
                              void* d_out, int out_size, void* d_ws, size_t ws_size,
                              hipStream_t stream) {
  const float* q      = (const float*)d_in[0];
  const float* w_qs   = (const float*)d_in[1];
  const float* w_ks   = (const float*)d_in[2];
  const float* w_vs   = (const float*)d_in[3];
  const float* w_rel  = (const float*)d_in[4];
  const float* ebias  = (const float*)d_in[5];
  const float* pbias  = (const float*)d_in[6];
  const float* w_out  = (const float*)d_in[7];
  const float* b_out  = (const float*)d_in[8];
  float* out = (float*)d_out;

  char* ws = (char*)d_ws;
  const size_t MB = 1u << 20;
  unsigned short* Xh    = (unsigned short*)(ws + 0 * MB);   // 2048x1024 fp16 (4MB)
  unsigned short* WqsT  = (unsigned short*)(ws + 4 * MB);   // 1024x1024 (2MB)
  unsigned short* WksT  = (unsigned short*)(ws + 6 * MB);
  unsigned short* WvsT  = (unsigned short*)(ws + 8 * MB);
  unsigned short* WoutT = (unsigned short*)(ws + 10 * MB);
  unsigned short* WrelT = (unsigned short*)(ws + 12 * MB);  // 1024x192 (0.375MB)
  unsigned short* pos   = (unsigned short*)(ws + 13 * MB);  // 2048x192 (0.75MB)
  float* Qproj          = (float*)(ws + 16 * MB);           // 2048x1024 f32 (8MB)
  float* Kproj          = (float*)(ws + 24 * MB);
  float* Vproj          = (float*)(ws + 32 * MB);
  float* relk           = (float*)(ws + 40 * MB);           // 2048x1024 f32 (8MB)
  unsigned short* Kh    = (unsigned short*)(ws + 48 * MB);  // 2048x1024 fp16
  unsigned short* relkh = (unsigned short*)(ws + 52 * MB);
  unsigned short* Vt    = (unsigned short*)(ws + 56 * MB);  // 16x128x1024 fp16
  unsigned short* attnO = (unsigned short*)(ws + 60 * MB);  // 2048x1024 fp16

  // 1. converts / transposes / positional embed
  cvt_f16_kernel<<<2048, 256, 0, stream>>>(q, Xh);
  transpose_w_kernel<<<dim3(32, 32), dim3(32, 8), 0, stream>>>(w_qs, WqsT, 1024, 1024);
  transpose_w_kernel<<<dim3(32, 32), dim3(32, 8), 0, stream>>>(w_ks, WksT, 1024, 1024);
  transpose_w_kernel<<<dim3(32, 32), dim3(32, 8), 0, stream>>>(w_vs, WvsT, 1024, 1024);
  transpose_w_kernel<<<dim3(32, 32), dim3(32, 8), 0, stream>>>(w_out, WoutT, 1024, 1024);
  transpose_w_kernel<<<dim3(32, 6), dim3(32, 8), 0, stream>>>(w_rel, WrelT, 192, 1024);
  posembed_kernel<<<8, 256, 0, stream>>>(pos);

  // 2. projections (QKV batched via grid.z), rel_k
  gemm_bt_kernel<<<dim3(16, 8, 3), 256, 0, stream>>>(Xh, WqsT, WksT, WvsT,
                                                     Qproj, Kproj, Vproj,
                                                     nullptr, 2048, 1024, 1024);
  gemm_bt_kernel<<<dim3(16, 8, 1), 256, 0, stream>>>(pos, WrelT, WrelT, WrelT,
                                                     relk, relk, relk,
                                                     nullptr, 2048, 1024, 192);

  // 3. fp16 preps for attention
  cvt_f16_kernel<<<2048, 256, 0, stream>>>(Kproj, Kh);
  cvt_f16_kernel<<<2048, 256, 0, stream>>>(relk, relkh);
  vt_prep_kernel<<<dim3(32, 4, 16), dim3(32, 8), 0, stream>>>(Vproj, Vt);

  // 4. fused attention
  attn_kernel<<<dim3(16, 16), 256, 0, stream>>>(Qproj, Kh, Vt, relkh, ebias, pbias, attnO);

  // 5. output projection + bias
  gemm_bt_kernel<<<dim3(16, 8, 1), 256, 0, stream>>>(attnO, WoutT, WoutT, WoutT,
                                                     out, out, out,
                                                     b_out, 2048, 1024, 1024);
}

// Round 3
// 172.221 us; speedup vs baseline: 1.2244x; 1.2244x over previous
//
#include <hip/hip_runtime.h>
#include <hip/hip_fp16.h>

typedef __attribute__((ext_vector_type(8))) _Float16 f16x8;
typedef __attribute__((ext_vector_type(4))) float f32x4;

#define MFMA16(a, b, c) __builtin_amdgcn_mfma_f32_16x16x32_f16((a), (b), (c), 0, 0, 0)

__device__ __forceinline__ unsigned short f2h(float f) {
  __half h = __float2half(f);
  return __half_as_ushort(h);
}

__device__ __forceinline__ void gll16(const void* g, void* l) {
  __builtin_amdgcn_global_load_lds(
      (const __attribute__((address_space(1))) unsigned int*)g,
      (__attribute__((address_space(3))) unsigned int*)l, 16, 0, 0);
}

// ---------------- f32 -> fp16 convert (vectorized) ----------------
__global__ void cvt_f16_kernel(const float* __restrict__ X, unsigned short* __restrict__ Y) {
  size_t i = ((size_t)blockIdx.x * blockDim.x + threadIdx.x) * 4;
  float4 v = *reinterpret_cast<const float4*>(X + i);
  ushort4 o;
  o.x = f2h(v.x); o.y = f2h(v.y); o.z = f2h(v.z); o.w = f2h(v.w);
  *reinterpret_cast<ushort4*>(Y + i) = o;
}

// ---------------- weight transpose f32(RxC) -> fp16(CxR) ----------------
__global__ void transpose_w_kernel(const float* __restrict__ W, unsigned short* __restrict__ WT,
                                   int R, int C) {
  __shared__ float tile[32][33];
  int c0 = blockIdx.x * 32, r0 = blockIdx.y * 32;
  int tx = threadIdx.x, ty = threadIdx.y;  // 32 x 8
#pragma unroll
  for (int i = 0; i < 32; i += 8)
    tile[ty + i][tx] = W[(size_t)(r0 + ty + i) * C + c0 + tx];
  __syncthreads();
#pragma unroll
  for (int i = 0; i < 32; i += 8)
    WT[(size_t)(c0 + ty + i) * R + r0 + tx] = f2h(tile[tx][ty + i]);
}

// ---------------- positional embedding: pos[2048][192] fp16 (row 2047 = 0) ----------------
__global__ void posembed_kernel(unsigned short* __restrict__ pos) {
  int d = blockIdx.x * blockDim.x + threadIdx.x;
  if (d >= 2048) return;
  unsigned short* row = pos + (size_t)d * 192;
  if (d == 2047) {
    for (int j = 0; j < 192; ++j) row[j] = 0;
    return;
  }
  float dist = (float)d - 1023.0f;
  float absd = fabsf(dist);
  float sgnp = (dist > 0.0f) ? 1.0f : ((dist < 0.0f) ? -1.0f : 0.0f);
  float gam[32];
  float maxp = 0.0f;
#pragma unroll
  for (int j = 0; j < 32; ++j) {
    float hl = exp2f(3.0f + (float)j * (7.0f / 31.0f));
    float fe = exp2f(-absd / hl);
    float cw = exp2f((float)(j + 1)) - 1.0f;
    float fc = (cw > absd) ? 1.0f : 0.0f;
    float jp = (float)(j + 1);
    float conc = 4.0f * jp * jp;
    float rate = 0.125f * jp;
    float lu = (conc - 1.0f) * logf(absd) - rate * absd;
    float ln_ = lgammaf(conc) - conc * logf(rate);
    float p = expf(lu - ln_) + 1e-8f;
    gam[j] = p;
    maxp = fmaxf(maxp, p);
    row[j] = f2h(fe);
    row[32 + j] = f2h(fc);
  }
  float inv = 1.0f / maxp;
#pragma unroll
  for (int j = 0; j < 32; ++j) row[64 + j] = f2h(gam[j] * inv);
  for (int j = 0; j < 96; ++j) {
    unsigned short v = row[j];
    unsigned short o;
    if (sgnp == 0.0f) o = 0;
    else if (sgnp > 0.0f) o = v;
    else o = (unsigned short)(v ^ 0x8000u);
    row[96 + j] = o;
  }
}

// ---------------- fp16 GEMM (m97 structure): C = A[M,K] @ BT[N,K]^T ----------------
// 128x128 tile, 4 waves, BK=64, global_load_lds w16, XOR-swizzled (both-sides).
// Output: fp16 D (if C32==null) or f32 C32 (+bias).
__global__ __launch_bounds__(256) void gemm16_kernel(
    const unsigned short* __restrict__ A,
    const unsigned short* __restrict__ BT0, const unsigned short* __restrict__ BT1,
    const unsigned short* __restrict__ BT2,
    unsigned short* __restrict__ D0, unsigned short* __restrict__ D1,
    unsigned short* __restrict__ D2,
    float* __restrict__ C32, const float* __restrict__ bias,
    int M, int N, int K) {
  __shared__ unsigned short As[128][64];  // linear (gll dest), logically XOR-swizzled
  __shared__ unsigned short Bs[128][64];
  const unsigned short* BT = (blockIdx.z == 0) ? BT0 : ((blockIdx.z == 1) ? BT1 : BT2);
  unsigned short* D = (blockIdx.z == 0) ? D0 : ((blockIdx.z == 1) ? D1 : D2);

  int tid = threadIdx.x, wave = tid >> 6, lane = tid & 63;
  int g = lane >> 4, r16 = lane & 15;
  int wr = wave >> 1, wc = wave & 1;
  int m0 = blockIdx.x * 128, n0 = blockIdx.y * 128;
  int srow = wave * 32 + (lane >> 3);  // + 8*i
  int scb = lane & 7;                  // physical 16B slot within row

  f32x4 acc[4][4] = {};

  for (int k0 = 0; k0 < K; k0 += 64) {
    __syncthreads();
#pragma unroll
    for (int i = 0; i < 4; ++i) {
      int row = srow + i * 8;
      int cb = scb ^ (row & 7);  // pre-swizzled global source, linear LDS dest
      gll16(A + (size_t)(m0 + row) * K + k0 + cb * 8, &As[row][scb * 8]);
      gll16(BT + (size_t)(n0 + row) * K + k0 + cb * 8, &Bs[row][scb * 8]);
    }
    asm volatile("s_waitcnt vmcnt(0)" ::: "memory");
    __syncthreads();

    f16x8 af[2][4], bfr[2][4];
#pragma unroll
    for (int kf = 0; kf < 2; ++kf) {
#pragma unroll
      for (int mt = 0; mt < 4; ++mt) {
        int R = wr * 64 + mt * 16 + r16;
        af[kf][mt] = *reinterpret_cast<const f16x8*>(&As[R][(((kf * 4 + g)) ^ (R & 7)) * 8]);
      }
#pragma unroll
      for (int nt = 0; nt < 4; ++nt) {
        int R = wc * 64 + nt * 16 + r16;
        bfr[kf][nt] = *reinterpret_cast<const f16x8*>(&Bs[R][(((kf * 4 + g)) ^ (R & 7)) * 8]);
      }
    }
#pragma unroll
    for (int kf = 0; kf < 2; ++kf)
#pragma unroll
      for (int mt = 0; mt < 4; ++mt)
#pragma unroll
        for (int nt = 0; nt < 4; ++nt)
          acc[mt][nt] = MFMA16(af[kf][mt], bfr[kf][nt], acc[mt][nt]);
  }

#pragma unroll
  for (int nt = 0; nt < 4; ++nt) {
    int col = n0 + wc * 64 + nt * 16 + r16;
    float bv = (C32 && bias) ? bias[col] : 0.0f;
#pragma unroll
    for (int mt = 0; mt < 4; ++mt) {
      int rowb = m0 + wr * 64 + mt * 16 + g * 4;
      if (C32) {
#pragma unroll
        for (int rg = 0; rg < 4; ++rg)
          C32[(size_t)(rowb + rg) * N + col] = acc[mt][nt][rg] + bv;
      } else {
#pragma unroll
        for (int rg = 0; rg < 4; ++rg)
          D[(size_t)(rowb + rg) * N + col] = f2h(acc[mt][nt][rg]);
      }
    }
  }
}

// ---------------- V transpose prep: Vh fp16 (2048x1024) -> Vt fp16 [bh][128][1024] ----------------
__global__ void vt_prep_kernel(const unsigned short* __restrict__ Vh, unsigned short* __restrict__ Vt) {
  __shared__ unsigned short tile[32][34];
  int bh = blockIdx.z;
  int b = bh >> 3, h = bh & 7;
  int l0 = blockIdx.x * 32, n0 = blockIdx.y * 32;
  int tx = threadIdx.x, ty = threadIdx.y;
#pragma unroll
  for (int i = 0; i < 32; i += 8)
    tile[ty + i][tx] = Vh[(size_t)(b * 1024 + l0 + ty + i) * 1024 + h * 128 + n0 + tx];
  __syncthreads();
#pragma unroll
  for (int i = 0; i < 32; i += 8)
    Vt[(size_t)bh * 131072 + (size_t)(n0 + ty + i) * 1024 + l0 + tx] = tile[tx][ty + i];
}

// ---------------- fused attention, split-K ----------------
// grid (L/64, 2, B*H); 4 waves; wave owns 16 q rows; BK=32; online softmax.
// Each block does k in [ks*512, ks*512+512); partial (O unnormalized, m, l) out.
__global__ __launch_bounds__(256) void attn_kernel(
    const unsigned short* __restrict__ Qh, const unsigned short* __restrict__ Kh,
    const unsigned short* __restrict__ Vt, const unsigned short* __restrict__ relkh,
    const float* __restrict__ eb, const float* __restrict__ pb,
    float* __restrict__ Opart, float* __restrict__ mlpart) {
  __shared__ unsigned short Ks[32][136];
  __shared__ unsigned short Vs[128][40];
  __shared__ unsigned short Rs[96][136];
  __shared__ float Ws[4][16][51];
  __shared__ unsigned short Ps[4][16][40];

  int tid = threadIdx.x;
  int wave = tid >> 6, lane = tid & 63;
  int g = lane >> 4, r16 = lane & 15;
  int ks = blockIdx.y;
  int bh = blockIdx.z;
  int b = bh >> 3, h = bh & 7;
  int q0 = blockIdx.x * 64;
  int q0w = q0 + wave * 16;
  const float scale = 0.0883883476483184f;  // 128^-0.5

  // ---- Q fragments (A-layout), two bias variants
  f16x8 qa[4], qbv[4];
  {
    int qrow = b * 1024 + q0w + r16;
    const unsigned short* qp = Qh + (size_t)qrow * 1024 + h * 128;
    const float* ebp = eb + h * 128;
    const float* pbp = pb + h * 128;
#pragma unroll
    for (int kf = 0; kf < 4; ++kf) {
      int dbase = kf * 32 + g * 8;
      uint4 qv = *reinterpret_cast<const uint4*>(qp + dbase);
      const __half* hv = reinterpret_cast<const __half*>(&qv);
      float4 e0 = *reinterpret_cast<const float4*>(ebp + dbase);
      float4 e1 = *reinterpret_cast<const float4*>(ebp + dbase + 4);
      float4 c0 = *reinterpret_cast<const float4*>(pbp + dbase);
      float4 c1 = *reinterpret_cast<const float4*>(pbp + dbase + 4);
      float ev[8] = {e0.x, e0.y, e0.z, e0.w, e1.x, e1.y, e1.z, e1.w};
      float bv[8] = {c0.x, c0.y, c0.z, c0.w, c1.x, c1.y, c1.z, c1.w};
      unsigned short ta[8], tb[8];
#pragma unroll
      for (int i = 0; i < 8; ++i) {
        float s = __half2float(hv[i]) * scale;
        ta[i] = f2h(s + ev[i]);
        tb[i] = f2h(s + bv[i]);
      }
      qa[kf] = *reinterpret_cast<f16x8*>(ta);
      qbv[kf] = *reinterpret_cast<f16x8*>(tb);
    }
  }

  float m_run[4], l_run[4];
#pragma unroll
  for (int rg = 0; rg < 4; ++rg) { m_run[rg] = -1e30f; l_run[rg] = 0.0f; }
  f32x4 o_acc[8] = {};

  for (int kt = ks * 16; kt < ks * 16 + 16; ++kt) {
    int k0 = kt * 32;
    __syncthreads();
    // stage K tile (32 x 128)
    {
      int rr = tid >> 3, cc = (tid & 7) * 16;
      const unsigned short* src = Kh + (size_t)(b * 1024 + k0 + rr) * 1024 + h * 128 + cc;
      uint4 v0 = *reinterpret_cast<const uint4*>(src);
      uint4 v1 = *reinterpret_cast<const uint4*>(src + 8);
      *reinterpret_cast<uint4*>(&Ks[rr][cc]) = v0;
      *reinterpret_cast<uint4*>(&Ks[rr][cc + 8]) = v1;
    }
    // stage V^T tile (128 v-dims x 32 k)
    {
      int rr = tid >> 1, cc = (tid & 1) * 16;
      const unsigned short* src = Vt + (size_t)bh * 131072 + (size_t)rr * 1024 + k0 + cc;
      uint4 v0 = *reinterpret_cast<const uint4*>(src);
      uint4 v1 = *reinterpret_cast<const uint4*>(src + 8);
      *reinterpret_cast<uint4*>(&Vs[rr][cc]) = v0;
      *reinterpret_cast<uint4*>(&Vs[rr][cc + 8]) = v1;
    }
    // stage rel_k span: rows base..base+95
    {
      int base = 960 + k0 - q0;
      int cc = (tid & 7) * 16;
#pragma unroll
      for (int j = 0; j < 3; ++j) {
        int i = (tid >> 3) + j * 32;
        const unsigned short* src = relkh + (size_t)(base + i) * 1024 + h * 128 + cc;
        uint4 v0 = *reinterpret_cast<const uint4*>(src);
        uint4 v1 = *reinterpret_cast<const uint4*>(src + 8);
        *reinterpret_cast<uint4*>(&Rs[i][cc]) = v0;
        *reinterpret_cast<uint4*>(&Rs[i][cc + 8]) = v1;
      }
    }
    __syncthreads();

    // S1 = Qa . K^T (16 x 32)
    f32x4 s0 = {0.f, 0.f, 0.f, 0.f}, s1 = {0.f, 0.f, 0.f, 0.f};
#pragma unroll
    for (int kf = 0; kf < 4; ++kf) {
      f16x8 kb0 = *reinterpret_cast<const f16x8*>(&Ks[r16][kf * 32 + g * 8]);
      f16x8 kb1 = *reinterpret_cast<const f16x8*>(&Ks[16 + r16][kf * 32 + g * 8]);
      s0 = MFMA16(qa[kf], kb0, s0);
      s1 = MFMA16(qa[kf], kb1, s1);
    }
    // W = Qb . RKspan^T (16 x 48)
    f32x4 w0 = {0.f, 0.f, 0.f, 0.f}, w1 = {0.f, 0.f, 0.f, 0.f}, w2 = {0.f, 0.f, 0.f, 0.f};
    int wbase = 48 - wave * 16;
#pragma unroll
    for (int kf = 0; kf < 4; ++kf) {
      f16x8 rb0 = *reinterpret_cast<const f16x8*>(&Rs[wbase + r16][kf * 32 + g * 8]);
      f16x8 rb1 = *reinterpret_cast<const f16x8*>(&Rs[wbase + 16 + r16][kf * 32 + g * 8]);
      f16x8 rb2 = *reinterpret_cast<const f16x8*>(&Rs[wbase + 32 + r16][kf * 32 + g * 8]);
      w0 = MFMA16(qbv[kf], rb0, w0);
      w1 = MFMA16(qbv[kf], rb1, w1);
      w2 = MFMA16(qbv[kf], rb2, w2);
    }
    // W -> per-wave LDS, diagonal gather: S2[q'][k'] = W[q'][k'-q'+15]
#pragma unroll
    for (int rg = 0; rg < 4; ++rg) {
      Ws[wave][g * 4 + rg][r16] = w0[rg];
      Ws[wave][g * 4 + rg][16 + r16] = w1[rg];
      Ws[wave][g * 4 + rg][32 + r16] = w2[rg];
    }
    float sv[2][4];
#pragma unroll
    for (int rg = 0; rg < 4; ++rg) {
      int qp = g * 4 + rg;
      sv[0][rg] = s0[rg] + Ws[wave][qp][r16 - qp + 15];
      sv[1][rg] = s1[rg] + Ws[wave][qp][r16 + 16 - qp + 15];
    }
    // online softmax
#pragma unroll
    for (int rg = 0; rg < 4; ++rg) {
      float mx = fmaxf(sv[0][rg], sv[1][rg]);
#pragma unroll
      for (int off = 8; off >= 1; off >>= 1) mx = fmaxf(mx, __shfl_xor(mx, off));
      float mnew = fmaxf(m_run[rg], mx);
      float scl = __expf(m_run[rg] - mnew);
      float e0 = __expf(sv[0][rg] - mnew);
      float e1 = __expf(sv[1][rg] - mnew);
      float rs = e0 + e1;
#pragma unroll
      for (int off = 8; off >= 1; off >>= 1) rs += __shfl_xor(rs, off);
      l_run[rg] = l_run[rg] * scl + rs;
      m_run[rg] = mnew;
#pragma unroll
      for (int nf = 0; nf < 8; ++nf) o_acc[nf][rg] *= scl;
      Ps[wave][g * 4 + rg][r16] = f2h(e0);
      Ps[wave][g * 4 + rg][16 + r16] = f2h(e1);
    }
    // PV: O += P (16x32) . V (32x128)
    f16x8 pf = *reinterpret_cast<const f16x8*>(&Ps[wave][r16][g * 8]);
#pragma unroll
    for (int nf = 0; nf < 8; ++nf) {
      f16x8 vb = *reinterpret_cast<const f16x8*>(&Vs[nf * 16 + r16][g * 8]);
      o_acc[nf] = MFMA16(pf, vb, o_acc[nf]);
    }
  }

  // epilogue: write unnormalized O (f32) + (m,l) partials
  size_t slice = (size_t)(ks * 16 + bh);
#pragma unroll
  for (int rg = 0; rg < 4; ++rg) {
    float* op = Opart + (slice * 1024 + q0w + g * 4 + rg) * 128;
#pragma unroll
    for (int nf = 0; nf < 8; ++nf) op[nf * 16 + r16] = o_acc[nf][rg];
  }
  if (r16 == 0) {
#pragma unroll
    for (int rg = 0; rg < 4; ++rg) {
      float2 ml = {m_run[rg], l_run[rg]};
      *reinterpret_cast<float2*>(mlpart + (slice * 1024 + q0w + g * 4 + rg) * 2) = ml;
    }
  }
}

// ---------------- combine two k-slices -> attnO fp16 ----------------
__global__ void combine_kernel(const float* __restrict__ Opart, const float* __restrict__ mlpart,
                               unsigned short* __restrict__ attnO) {
  int idx = blockIdx.x * 256 + threadIdx.x;  // 16*1024*32 threads
  int d4 = (idx & 31) * 4;
  int qq = (idx >> 5) & 1023;
  int bh = idx >> 15;
  size_t r0 = (size_t)bh * 1024 + qq;
  size_t r1 = (size_t)(16 + bh) * 1024 + qq;
  float2 ml0 = *reinterpret_cast<const float2*>(mlpart + r0 * 2);
  float2 ml1 = *reinterpret_cast<const float2*>(mlpart + r1 * 2);
  float m = fmaxf(ml0.x, ml1.x);
  float w0 = __expf(ml0.x - m), w1 = __expf(ml1.x - m);
  float inv = 1.0f / (w0 * ml0.y + w1 * ml1.y);
  float4 o0 = *reinterpret_cast<const float4*>(Opart + r0 * 128 + d4);
  float4 o1 = *reinterpret_cast<const float4*>(Opart + r1 * 128 + d4);
  ushort4 o;
  o.x = f2h((w0 * o0.x + w1 * o1.x) * inv);
  o.y = f2h((w0 * o0.y + w1 * o1.y) * inv);
  o.z = f2h((w0 * o0.z + w1 * o1.z) * inv);
  o.w = f2h((w0 * o0.w + w1 * o1.w) * inv);
  int b = bh >> 3, h = bh & 7;
  *reinterpret_cast<ushort4*>(attnO + ((size_t)(b * 1024 + qq)) * 1024 + h * 128 + d4) = o;
}

// ---------------- launch ----------------
extern "C" void kernel_launch(void* const* d_in, const int* in_sizes, int n_in,
                              void* d_out, int out_size, void* d_ws, size_t ws_size,
                              hipStream_t stream) {
  const float* q      = (const float*)d_in[0];
  const float* w_qs   = (const float*)d_in[1];
  const float* w_ks   = (const float*)d_in[2];
  const float* w_vs   = (const float*)d_in[3];
  const float* w_rel  = (const float*)d_in[4];
  const float* ebias  = (const float*)d_in[5];
  const float* pbias  = (const float*)d_in[6];
  const float* w_out  = (const float*)d_in[7];
  const float* b_out  = (const float*)d_in[8];
  float* out = (float*)d_out;

  char* ws = (char*)d_ws;
  const size_t MB = 1u << 20;
  unsigned short* Xh    = (unsigned short*)(ws + 0 * MB);   // 2048x1024 fp16
  unsigned short* WqsT  = (unsigned short*)(ws + 4 * MB);
  unsigned short* WksT  = (unsigned short*)(ws + 6 * MB);
  unsigned short* WvsT  = (unsigned short*)(ws + 8 * MB);
  unsigned short* WoutT = (unsigned short*)(ws + 10 * MB);
  unsigned short* WrelT = (unsigned short*)(ws + 12 * MB);  // 1024x192
  unsigned short* pos   = (unsigned short*)(ws + 13 * MB);  // 2048x192
  unsigned short* Qh    = (unsigned short*)(ws + 14 * MB);  // 2048x1024 fp16
  unsigned short* Kh    = (unsigned short*)(ws + 18 * MB);
  unsigned short* Vh    = (unsigned short*)(ws + 22 * MB);
  unsigned short* relkh = (unsigned short*)(ws + 26 * MB);  // 2048x1024 fp16
  unsigned short* Vt    = (unsigned short*)(ws + 30 * MB);  // 16x128x1024 fp16
  unsigned short* attnO = (unsigned short*)(ws + 34 * MB);  // 2048x1024 fp16
  float* Opart          = (float*)(ws + 38 * MB);           // 2x16x1024x128 f32 (16MB)
  float* mlpart         = (float*)(ws + 54 * MB);           // 2x16x1024x2 f32

  // 1. converts / transposes / positional embed
  cvt_f16_kernel<<<2048, 256, 0, stream>>>(q, Xh);
  transpose_w_kernel<<<dim3(32, 32), dim3(32, 8), 0, stream>>>(w_qs, WqsT, 1024, 1024);
  transpose_w_kernel<<<dim3(32, 32), dim3(32, 8), 0, stream>>>(w_ks, WksT, 1024, 1024);
  transpose_w_kernel<<<dim3(32, 32), dim3(32, 8), 0, stream>>>(w_vs, WvsT, 1024, 1024);
  transpose_w_kernel<<<dim3(32, 32), dim3(32, 8), 0, stream>>>(w_out, WoutT, 1024, 1024);
  transpose_w_kernel<<<dim3(32, 6), dim3(32, 8), 0, stream>>>(w_rel, WrelT, 192, 1024);
  posembed_kernel<<<8, 256, 0, stream>>>(pos);

  // 2. projections (QKV batched via grid.z) + rel_k, fp16 outputs
  gemm16_kernel<<<dim3(16, 8, 3), 256, 0, stream>>>(Xh, WqsT, WksT, WvsT,
                                                    Qh, Kh, Vh,
                                                    nullptr, nullptr, 2048, 1024, 1024);
  gemm16_kernel<<<dim3(16, 8, 1), 256, 0, stream>>>(pos, WrelT, WrelT, WrelT,
                                                    relkh, relkh, relkh,
                                                    nullptr, nullptr, 2048, 1024, 192);

  // 3. V^T prep
  vt_prep_kernel<<<dim3(32, 4, 16), dim3(32, 8), 0, stream>>>(Vh, Vt);

  // 4. fused attention (split-K over 2 slices) + combine
  attn_kernel<<<dim3(16, 2, 16), 256, 0, stream>>>(Qh, Kh, Vt, relkh, ebias, pbias,
                                                   Opart, mlpart);
  combine_kernel<<<2048, 256, 0, stream>>>(Opart, mlpart, attnO);

  // 5. output projection + bias (f32 out)
  gemm16_kernel<<<dim3(16, 8, 1), 256, 0, stream>>>(attnO, WoutT, WoutT, WoutT,
                                                    nullptr, nullptr, nullptr,
                                                    out, b_out, 2048, 1024, 1024);
}